// Round 3
// baseline (85.284 us; speedup 1.0000x reference)
//
#include <hip/hip_runtime.h>
#include <math.h>

#define BATCH  8
#define NPTS   4096
#define TPB    256
#define QPT    8                 // queries per thread (independent min chains)
#define QCHUNK (TPB * QPT)       // 2048 queries per block
#define NQC    (NPTS / QCHUNK)   // 2 query chunks
#define NCC    32                // candidate chunks (parallelism multiplier)
#define CTILE  (NPTS / NCC)      // 128 candidates per chunk
#define NQTOT  (2 * BATCH * NPTS) // 65536 total queries (both directions)

// Phase 1: block = (query chunk, candidate chunk, batch, dir).
// Candidates staged in LDS as (-2cx,-2cy,-2cz,||c||^2): 3 FMA + 1 min per pair.
// QPT=8 -> 32 VALU wave-instrs (16 CU-cyc) per 12-cyc ds_read_b128: VALU-bound.
// Stores clamped partial minima (clamp commutes with the later min) to
// partial[cc][dir][b][q] -- contiguous 32 B per thread, no atomics, no init.
__global__ __launch_bounds__(TPB) void chamfer_min_kernel(
    const float* __restrict__ input,
    const float* __restrict__ target,
    float* __restrict__ partial)
{
    const int dir = blockIdx.z;
    const int b   = blockIdx.y;
    const int qc  = blockIdx.x & (NQC - 1);
    const int cc  = blockIdx.x >> 1;          // NQC == 2

    const float* __restrict__ qp = (dir ? target : input) + (size_t)b * NPTS * 3;
    const float* __restrict__ cp = (dir ? input  : target) + (size_t)b * NPTS * 3;

    __shared__ float4 cand[CTILE];
    if (threadIdx.x < CTILE) {
        const int c = cc * CTILE + threadIdx.x;
        const float cx = cp[3 * c + 0];
        const float cy = cp[3 * c + 1];
        const float cz = cp[3 * c + 2];
        cand[threadIdx.x] = make_float4(-2.0f * cx, -2.0f * cy, -2.0f * cz,
                                        fmaf(cx, cx, fmaf(cy, cy, cz * cz)));
    }

    // 8 contiguous queries per thread = 24 floats = 6 float4 loads.
    const int q0 = qc * QCHUNK + (int)threadIdx.x * QPT;
    float qv[3 * QPT];
    {
        const float4* qp4 = (const float4*)(qp + 3 * q0);
        #pragma unroll
        for (int j = 0; j < 6; ++j) {
            const float4 v = qp4[j];
            qv[4 * j + 0] = v.x; qv[4 * j + 1] = v.y;
            qv[4 * j + 2] = v.z; qv[4 * j + 3] = v.w;
        }
    }
    float pmin[QPT];
    #pragma unroll
    for (int k = 0; k < QPT; ++k) pmin[k] = 3.4e38f;
    __syncthreads();

    #pragma unroll 2
    for (int m = 0; m < CTILE; ++m) {
        const float4 c = cand[m];                 // LDS broadcast read
        #pragma unroll
        for (int k = 0; k < QPT; ++k) {
            const float t = fmaf(qv[3 * k + 0], c.x,
                            fmaf(qv[3 * k + 1], c.y,
                            fmaf(qv[3 * k + 2], c.z, c.w)));   // ||c||^2 - 2 x.c
            pmin[k] = fminf(pmin[k], t);
        }
    }

    // v = max(pmin + ||x||^2, 0); store 8 contiguous floats (2 float4s).
    float res[QPT];
    #pragma unroll
    for (int k = 0; k < QPT; ++k) {
        const float x2 = fmaf(qv[3 * k + 0], qv[3 * k + 0],
                         fmaf(qv[3 * k + 1], qv[3 * k + 1],
                              qv[3 * k + 2] * qv[3 * k + 2]));
        res[k] = fmaxf(pmin[k] + x2, 0.0f);
    }
    float4* pout = (float4*)(partial + (size_t)cc * NQTOT +
                             ((size_t)(dir * BATCH + b)) * NPTS + q0);
    pout[0] = make_float4(res[0], res[1], res[2], res[3]);
    pout[1] = make_float4(res[4], res[5], res[6], res[7]);
}

// Phase 2: per query, min over the NCC candidate-chunk partials (coalesced
// dword loads), then block-sum and one atomicAdd.
__global__ __launch_bounds__(TPB) void chamfer_reduce_kernel(
    const float* __restrict__ partial, float* __restrict__ out)
{
    const int g = blockIdx.x * TPB + (int)threadIdx.x;   // global query id
    float v = partial[g];
    #pragma unroll
    for (int cc = 1; cc < NCC; ++cc)
        v = fminf(v, partial[(size_t)cc * NQTOT + g]);

    float s = v;
    #pragma unroll
    for (int off = 32; off > 0; off >>= 1)
        s += __shfl_down(s, off, 64);

    __shared__ float wsum[TPB / 64];
    if ((threadIdx.x & 63) == 0) wsum[threadIdx.x >> 6] = s;
    __syncthreads();
    if (threadIdx.x == 0) {
        const float t = wsum[0] + wsum[1] + wsum[2] + wsum[3];
        atomicAdd(out, t * (1.0f / (float)(BATCH * NPTS)));
    }
}

extern "C" void kernel_launch(void* const* d_in, const int* in_sizes, int n_in,
                              void* d_out, int out_size, void* d_ws, size_t ws_size,
                              hipStream_t stream) {
    const float* input  = (const float*)d_in[0];   // [B, N, 3] fp32
    const float* target = (const float*)d_in[1];   // [B, M, 3] fp32
    float* out = (float*)d_out;
    float* partial = (float*)d_ws;                 // NCC * 65536 floats = 8 MB

    hipMemsetAsync(out, 0, sizeof(float), stream); // harness poisons d_out

    dim3 grid1(NQC * NCC, BATCH, 2);               // 64 x 8 x 2 = 1024 blocks
    chamfer_min_kernel<<<grid1, dim3(TPB), 0, stream>>>(input, target, partial);

    chamfer_reduce_kernel<<<dim3(NQTOT / TPB), dim3(TPB), 0, stream>>>(partial, out);
}